// Round 1
// baseline (383.090 us; speedup 1.0000x reference)
//
#include <hip/hip_runtime.h>
#include <stdint.h>

#define D_MODEL 1024
#define NHEAD 16
#define HDIM 64
#define BATCH 4
#define SEQ 2048
#define BS (BATCH*SEQ)      // 8192 rows
#define NQKV (3*D_MODEL)    // 3072
#define BHEADS (BATCH*NHEAD) // 64

typedef __bf16 bf16x8 __attribute__((ext_vector_type(8)));
typedef float f32x4 __attribute__((ext_vector_type(4)));

__device__ __forceinline__ unsigned short f2bf(float f) {
    union { float f; unsigned u; } v; v.f = f;
    unsigned r = (v.u + 0x7FFFu + ((v.u >> 16) & 1u)) >> 16;
    return (unsigned short)r;
}
__device__ __forceinline__ float bf2f(unsigned short b) {
    union { unsigned u; float f; } v; v.u = ((unsigned)b) << 16;
    return v.f;
}

// ---------------- x f32 -> bf16 ----------------
__global__ __launch_bounds__(256) void k_cvt_x(const float4* __restrict__ x,
                                               uint2* __restrict__ o) {
    int i = blockIdx.x * 256 + threadIdx.x;   // 2,097,152 threads * 4 floats
    float4 v = x[i];
    uint2 r;
    r.x = (unsigned)f2bf(v.x) | ((unsigned)f2bf(v.y) << 16);
    r.y = (unsigned)f2bf(v.z) | ((unsigned)f2bf(v.w) << 16);
    o[i] = r;
}

// ------------- weight transpose: in[K=1024][ndim] f32 -> out[ndim][1024] bf16 -------------
__global__ __launch_bounds__(256) void k_transpose(const float* __restrict__ in,
                                                   unsigned short* __restrict__ out,
                                                   int ndim) {
    __shared__ float tile[64][65];
    const int n0 = blockIdx.x * 64, k0 = blockIdx.y * 64, tid = threadIdx.x;
#pragma unroll
    for (int i = 0; i < 16; i++) {
        int f = i * 256 + tid; int r = f >> 6, c = f & 63;
        tile[r][c] = in[(size_t)(k0 + r) * ndim + n0 + c];
    }
    __syncthreads();
#pragma unroll
    for (int i = 0; i < 16; i++) {
        int f = i * 256 + tid; int n = f >> 6, kq = f & 63;
        out[(size_t)(n0 + n) * 1024 + k0 + kq] = f2bf(tile[kq][n]);
    }
}

// ---------------- GEMM: C[M][N] = A[M][1024] * Bt[N][1024]^T (bf16 in, f32 acc) ----------------
// MODE 0: qkv epilogue -> scatter into q[bh][s][64], k[bh][s][64], vT[bh][d][s] (bf16)
// MODE 1: plain f32 C write (N assumed 1024)
template<int MODE>
__global__ __launch_bounds__(256) void k_gemm(const unsigned short* __restrict__ A,
                                              const unsigned short* __restrict__ Bt,
                                              float* __restrict__ Cout,
                                              unsigned short* __restrict__ qo,
                                              unsigned short* __restrict__ ko,
                                              unsigned short* __restrict__ vto) {
    __shared__ unsigned short As[128][72];
    __shared__ unsigned short Bs[128][72];
    const int tid = threadIdx.x, lane = tid & 63, wid = tid >> 6;
    const int l16 = lane & 15, lq = lane >> 4;
    const int wr = wid >> 1, wc = wid & 1;
    const int M0 = blockIdx.x * 128, N0 = blockIdx.y * 128;

    f32x4 acc[4][4] = {};

    for (int k0 = 0; k0 < 1024; k0 += 64) {
#pragma unroll
        for (int i = 0; i < 4; i++) {
            int ch = i * 256 + tid; int r = ch >> 3, c = (ch & 7) * 8;
            *(bf16x8*)&As[r][c] = *(const bf16x8*)(A  + (size_t)(M0 + r) * 1024 + k0 + c);
            *(bf16x8*)&Bs[r][c] = *(const bf16x8*)(Bt + (size_t)(N0 + r) * 1024 + k0 + c);
        }
        __syncthreads();
#pragma unroll
        for (int kk = 0; kk < 2; kk++) {
            bf16x8 af[4], bfr[4];
#pragma unroll
            for (int m = 0; m < 4; m++)
                af[m] = *(const bf16x8*)&As[wr * 64 + m * 16 + l16][kk * 32 + lq * 8];
#pragma unroll
            for (int n = 0; n < 4; n++)
                bfr[n] = *(const bf16x8*)&Bs[wc * 64 + n * 16 + l16][kk * 32 + lq * 8];
#pragma unroll
            for (int m = 0; m < 4; m++)
#pragma unroll
                for (int n = 0; n < 4; n++)
                    acc[m][n] = __builtin_amdgcn_mfma_f32_16x16x32_bf16(af[m], bfr[n], acc[m][n], 0, 0, 0);
        }
        __syncthreads();
    }

#pragma unroll
    for (int m = 0; m < 4; m++) {
#pragma unroll
        for (int n = 0; n < 4; n++) {
#pragma unroll
            for (int r = 0; r < 4; r++) {
                int row = M0 + wr * 64 + m * 16 + lq * 4 + r;
                int col = N0 + wc * 64 + n * 16 + l16;
                float val = acc[m][n][r];
                if (MODE == 1) {
                    Cout[(size_t)row * 1024 + col] = val;
                } else {
                    int which = col >> 10, h = (col >> 6) & 15, d = col & 63;
                    int b = row >> 11, s = row & 2047, bh = (b << 4) + h;
                    unsigned short bv = f2bf(val);
                    if (which == 0)      qo[((size_t)bh * SEQ + s) * 64 + d] = bv;
                    else if (which == 1) ko[((size_t)bh * SEQ + s) * 64 + d] = bv;
                    else                 vto[((size_t)bh * 64 + d) * SEQ + s] = bv;
                }
            }
        }
    }
}

// ---------------- per-head LayerNorm on q,k (in place, bf16) ----------------
__global__ __launch_bounds__(256) void k_ln(unsigned short* __restrict__ q,
                                            unsigned short* __restrict__ k,
                                            const float* __restrict__ qg, const float* __restrict__ qb,
                                            const float* __restrict__ kg, const float* __restrict__ kb) {
    const int wid = threadIdx.x >> 6, lane = threadIdx.x & 63;
    size_t row = (size_t)blockIdx.x * 4 + wid;   // 131072 rows of 64
    unsigned short* p = blockIdx.y ? k : q;
    const float* g  = blockIdx.y ? kg : qg;
    const float* bb = blockIdx.y ? kb : qb;
    float v = bf2f(p[row * 64 + lane]);
    float s = v;
#pragma unroll
    for (int m = 32; m; m >>= 1) s += __shfl_xor(s, m);
    float mean = s * (1.0f / 64.0f);
    float d = v - mean, sq = d * d;
#pragma unroll
    for (int m = 32; m; m >>= 1) sq += __shfl_xor(sq, m);
    float rs = rsqrtf(sq * (1.0f / 64.0f) + 1e-5f);
    p[row * 64 + lane] = f2bf(d * rs * g[lane] + bb[lane]);
}

// ---------------- flash attention: q[bh][s][64], k[bh][s][64], vT[bh][d][s] -> aout[b*S+s][h*64+d] bf16 ----------------
__global__ __launch_bounds__(256) void k_flash(const unsigned short* __restrict__ q,
                                               const unsigned short* __restrict__ k,
                                               const unsigned short* __restrict__ vt,
                                               unsigned short* __restrict__ aout) {
    __shared__ unsigned short Ks[64][72];
    __shared__ unsigned short Vs[64][72];
    __shared__ unsigned short Ps[4][16][72];
    const int tid = threadIdx.x, lane = tid & 63, wid = tid >> 6;
    const int l16 = lane & 15, lq = lane >> 4;
    const int bh = blockIdx.y;
    const int q0 = blockIdx.x * 64 + wid * 16;

    bf16x8 aq[2];
#pragma unroll
    for (int kk = 0; kk < 2; kk++)
        aq[kk] = *(const bf16x8*)(q + ((size_t)bh * SEQ + q0 + l16) * 64 + kk * 32 + lq * 8);

    f32x4 o[4] = {};
    float m_run[4] = {-1e30f, -1e30f, -1e30f, -1e30f};
    float l_run[4] = {0.f, 0.f, 0.f, 0.f};

    for (int t0 = 0; t0 < SEQ; t0 += 64) {
#pragma unroll
        for (int i = 0; i < 2; i++) {
            int ch = i * 256 + tid; int r = ch >> 3, c = (ch & 7) * 8;
            *(bf16x8*)&Ks[r][c] = *(const bf16x8*)(k  + ((size_t)bh * SEQ + t0 + r) * 64 + c);
            *(bf16x8*)&Vs[r][c] = *(const bf16x8*)(vt + ((size_t)bh * 64 + r) * SEQ + t0 + c);
        }
        __syncthreads();

        f32x4 sa[4] = {};
#pragma unroll
        for (int nb = 0; nb < 4; nb++) {
#pragma unroll
            for (int kk = 0; kk < 2; kk++) {
                bf16x8 bk = *(const bf16x8*)&Ks[nb * 16 + l16][kk * 32 + lq * 8];
                sa[nb] = __builtin_amdgcn_mfma_f32_16x16x32_bf16(aq[kk], bk, sa[nb], 0, 0, 0);
            }
        }

        float pe[4][4];
#pragma unroll
        for (int r = 0; r < 4; r++) {
            float mx = -1e30f;
#pragma unroll
            for (int nb = 0; nb < 4; nb++) { pe[nb][r] = sa[nb][r] * 0.125f; mx = fmaxf(mx, pe[nb][r]); }
#pragma unroll
            for (int m = 1; m < 16; m <<= 1) mx = fmaxf(mx, __shfl_xor(mx, m));
            float mn = fmaxf(m_run[r], mx);
            float scale = __expf(m_run[r] - mn);
            float rsum = 0.f;
#pragma unroll
            for (int nb = 0; nb < 4; nb++) { float e = __expf(pe[nb][r] - mn); pe[nb][r] = e; rsum += e; }
#pragma unroll
            for (int m = 1; m < 16; m <<= 1) rsum += __shfl_xor(rsum, m);
            m_run[r] = mn;
            l_run[r] = l_run[r] * scale + rsum;
#pragma unroll
            for (int db = 0; db < 4; db++) o[db][r] *= scale;
#pragma unroll
            for (int nb = 0; nb < 4; nb++) Ps[wid][lq * 4 + r][nb * 16 + l16] = f2bf(pe[nb][r]);
        }

        bf16x8 ap[2];
        ap[0] = *(const bf16x8*)&Ps[wid][l16][lq * 8];
        ap[1] = *(const bf16x8*)&Ps[wid][l16][32 + lq * 8];
#pragma unroll
        for (int db = 0; db < 4; db++) {
#pragma unroll
            for (int kk = 0; kk < 2; kk++) {
                bf16x8 bv = *(const bf16x8*)&Vs[db * 16 + l16][kk * 32 + lq * 8];
                o[db] = __builtin_amdgcn_mfma_f32_16x16x32_bf16(ap[kk], bv, o[db], 0, 0, 0);
            }
        }
        __syncthreads();
    }

    const int b = bh >> 4, h = bh & 15;
#pragma unroll
    for (int db = 0; db < 4; db++) {
#pragma unroll
        for (int r = 0; r < 4; r++) {
            float val = o[db][r] / l_run[r];
            size_t row = (size_t)b * SEQ + q0 + lq * 4 + r;
            aout[row * 1024 + h * 64 + db * 16 + l16] = f2bf(val);
        }
    }
}

extern "C" void kernel_launch(void* const* d_in, const int* in_sizes, int n_in,
                              void* d_out, int out_size, void* d_ws, size_t ws_size,
                              hipStream_t stream) {
    const float* x     = (const float*)d_in[0];
    const float* wqkv  = (const float*)d_in[1];
    const float* wproj = (const float*)d_in[2];
    const float* qg    = (const float*)d_in[3];
    const float* qb    = (const float*)d_in[4];
    const float* kg    = (const float*)d_in[5];
    const float* kb    = (const float*)d_in[6];
    float* out = (float*)d_out;

    char* ws = (char*)d_ws;
    unsigned short* xbf    = (unsigned short*)(ws);                       // 16 MB
    unsigned short* wqkvT  = (unsigned short*)(ws + (16llu << 20));       // 6 MB
    unsigned short* wprojT = (unsigned short*)(ws + (22llu << 20));       // 2 MB
    unsigned short* qraw   = (unsigned short*)(ws + (24llu << 20));       // 16 MB
    unsigned short* kraw   = (unsigned short*)(ws + (40llu << 20));       // 16 MB
    unsigned short* vtr    = (unsigned short*)(ws + (56llu << 20));       // 16 MB
    unsigned short* aattn  = (unsigned short*)(ws + (72llu << 20));       // 16 MB (total 88 MB)

    hipLaunchKernelGGL(k_cvt_x, dim3(8192), dim3(256), 0, stream, (const float4*)x, (uint2*)xbf);
    hipLaunchKernelGGL(k_transpose, dim3(48, 16), dim3(256), 0, stream, wqkv, wqkvT, 3072);
    hipLaunchKernelGGL(k_transpose, dim3(16, 16), dim3(256), 0, stream, wproj, wprojT, 1024);
    hipLaunchKernelGGL((k_gemm<0>), dim3(64, 24), dim3(256), 0, stream, xbf, wqkvT, (float*)nullptr, qraw, kraw, vtr);
    hipLaunchKernelGGL(k_ln, dim3(32768, 2), dim3(256), 0, stream, qraw, kraw, qg, qb, kg, kb);
    hipLaunchKernelGGL(k_flash, dim3(32, 64), dim3(256), 0, stream, qraw, kraw, vtr, aattn);
    hipLaunchKernelGGL((k_gemm<1>), dim3(64, 8), dim3(256), 0, stream, aattn, wprojT, out,
                       (unsigned short*)nullptr, (unsigned short*)nullptr, (unsigned short*)nullptr);
}

// Round 2
// 302.907 us; speedup vs baseline: 1.2647x; 1.2647x over previous
//
#include <hip/hip_runtime.h>
#include <stdint.h>

#define D_MODEL 1024
#define NHEAD 16
#define HDIM 64
#define BATCH 4
#define SEQ 2048
#define BS (BATCH*SEQ)      // 8192 rows
#define NQKV (3*D_MODEL)    // 3072
#define BHEADS (BATCH*NHEAD) // 64

typedef __bf16 bf16x8 __attribute__((ext_vector_type(8)));
typedef __bf16 bf16x2 __attribute__((ext_vector_type(2)));
typedef float f32x4 __attribute__((ext_vector_type(4)));
typedef float f32x2 __attribute__((ext_vector_type(2)));

__device__ __forceinline__ unsigned short f2bf(float f) {
    union { __bf16 b; unsigned short s; } u; u.b = (__bf16)f; return u.s;
}
__device__ __forceinline__ float bf2f(unsigned short b) {
    union { unsigned u; float f; } v; v.u = ((unsigned)b) << 16;
    return v.f;
}
__device__ __forceinline__ unsigned pack_bf16(float a, float b) {
    f32x2 t; t[0] = a; t[1] = b;
    bf16x2 r = __builtin_convertvector(t, bf16x2);
    union { bf16x2 v; unsigned u; } u; u.v = r; return u.u;
}

typedef __attribute__((address_space(3))) void lds_void_t;
typedef const __attribute__((address_space(1))) void glb_void_t;
__device__ __forceinline__ void gl2lds16(const void* g, void* l) {
    __builtin_amdgcn_global_load_lds((glb_void_t*)g, (lds_void_t*)l, 16, 0, 0);
}

// ---------------- x f32 -> bf16 ----------------
__global__ __launch_bounds__(256) void k_cvt_x(const float4* __restrict__ x,
                                               uint2* __restrict__ o) {
    int i = blockIdx.x * 256 + threadIdx.x;
    float4 v = x[i];
    uint2 r;
    r.x = (unsigned)f2bf(v.x) | ((unsigned)f2bf(v.y) << 16);
    r.y = (unsigned)f2bf(v.z) | ((unsigned)f2bf(v.w) << 16);
    o[i] = r;
}

// ------------- weight transpose: in[K=1024][ndim] f32 -> out[ndim][1024] bf16 -------------
__global__ __launch_bounds__(256) void k_transpose(const float* __restrict__ in,
                                                   unsigned short* __restrict__ out,
                                                   int ndim) {
    __shared__ float tile[64][65];
    const int n0 = blockIdx.x * 64, k0 = blockIdx.y * 64, tid = threadIdx.x;
#pragma unroll
    for (int i = 0; i < 16; i++) {
        int f = i * 256 + tid; int r = f >> 6, c = f & 63;
        tile[r][c] = in[(size_t)(k0 + r) * ndim + n0 + c];
    }
    __syncthreads();
#pragma unroll
    for (int i = 0; i < 16; i++) {
        int f = i * 256 + tid; int n = f >> 6, kq = f & 63;
        out[(size_t)(n0 + n) * 1024 + k0 + kq] = f2bf(tile[kq][n]);
    }
}

// ---------------- GEMM: C[M][N] = A[M][1024] * Bt[N][1024]^T (bf16 in, f32 acc) ----------------
// global_load_lds staging (m97 pattern): linear LDS tiles, wave-uniform base + lane*16B.
// MODE 0: qkv epilogue -> scatter q[bh][s][64], k[bh][s][64], vT[bh][d][s] (bf16)
// MODE 1: plain f32 C write (N assumed 1024)
template<int MODE>
__global__ __launch_bounds__(256) void k_gemm(const unsigned short* __restrict__ A,
                                              const unsigned short* __restrict__ Bt,
                                              float* __restrict__ Cout,
                                              unsigned short* __restrict__ qo,
                                              unsigned short* __restrict__ ko,
                                              unsigned short* __restrict__ vto) {
    __shared__ __align__(16) unsigned short As[128 * 64];
    __shared__ __align__(16) unsigned short Bs[128 * 64];
    const int tid = threadIdx.x, lane = tid & 63, wid = tid >> 6;
    const int l16 = lane & 15, lq = lane >> 4;
    const int wr = wid >> 1, wc = wid & 1;
    const int M0 = blockIdx.x * 128, N0 = blockIdx.y * 128;

    f32x4 acc[4][4] = {};

    for (int k0 = 0; k0 < 1024; k0 += 64) {
#pragma unroll
        for (int i = 0; i < 4; i++) {
            int ch = i * 256 + tid;                 // per-lane chunk index
            int r = ch >> 3, c = (ch & 7) * 8;
            int ldsbase = (i * 256 + wid * 64) * 8; // wave-uniform element offset
            gl2lds16(A  + (size_t)(M0 + r) * 1024 + k0 + c, &As[ldsbase]);
            gl2lds16(Bt + (size_t)(N0 + r) * 1024 + k0 + c, &Bs[ldsbase]);
        }
        __syncthreads();   // drains vmcnt(0) -> global_load_lds landed
#pragma unroll
        for (int kk = 0; kk < 2; kk++) {
            bf16x8 af[4], bfr[4];
#pragma unroll
            for (int m = 0; m < 4; m++)
                af[m] = *(const bf16x8*)&As[(wr * 64 + m * 16 + l16) * 64 + kk * 32 + lq * 8];
#pragma unroll
            for (int n = 0; n < 4; n++)
                bfr[n] = *(const bf16x8*)&Bs[(wc * 64 + n * 16 + l16) * 64 + kk * 32 + lq * 8];
#pragma unroll
            for (int m = 0; m < 4; m++)
#pragma unroll
                for (int n = 0; n < 4; n++)
                    acc[m][n] = __builtin_amdgcn_mfma_f32_16x16x32_bf16(af[m], bfr[n], acc[m][n], 0, 0, 0);
        }
        __syncthreads();
    }

#pragma unroll
    for (int m = 0; m < 4; m++) {
#pragma unroll
        for (int n = 0; n < 4; n++) {
#pragma unroll
            for (int r = 0; r < 4; r++) {
                int row = M0 + wr * 64 + m * 16 + lq * 4 + r;
                int col = N0 + wc * 64 + n * 16 + l16;
                float val = acc[m][n][r];
                if (MODE == 1) {
                    Cout[(size_t)row * 1024 + col] = val;
                } else {
                    int which = col >> 10, h = (col >> 6) & 15, d = col & 63;
                    int b = row >> 11, s = row & 2047, bh = (b << 4) + h;
                    unsigned short bv = f2bf(val);
                    if (which == 0)      qo[((size_t)bh * SEQ + s) * 64 + d] = bv;
                    else if (which == 1) ko[((size_t)bh * SEQ + s) * 64 + d] = bv;
                    else                 vto[((size_t)bh * 64 + d) * SEQ + s] = bv;
                }
            }
        }
    }
}

// ---------------- per-head LayerNorm on q,k (in place, bf16) ----------------
// q rows additionally scaled by log2(e)/8 so flash softmax runs in exp2 domain.
__global__ __launch_bounds__(256) void k_ln(unsigned short* __restrict__ q,
                                            unsigned short* __restrict__ k,
                                            const float* __restrict__ qg, const float* __restrict__ qb,
                                            const float* __restrict__ kg, const float* __restrict__ kb) {
    const int wid = threadIdx.x >> 6, lane = threadIdx.x & 63;
    size_t row = (size_t)blockIdx.x * 4 + wid;
    unsigned short* p = blockIdx.y ? k : q;
    const float* g  = blockIdx.y ? kg : qg;
    const float* bb = blockIdx.y ? kb : qb;
    const float c = blockIdx.y ? 1.0f : 0.18033688011112042f;  // log2(e)/8 folded into q
    float v = bf2f(p[row * 64 + lane]);
    float s = v;
#pragma unroll
    for (int m = 32; m; m >>= 1) s += __shfl_xor(s, m);
    float mean = s * (1.0f / 64.0f);
    float d = v - mean, sq = d * d;
#pragma unroll
    for (int m = 32; m; m >>= 1) sq += __shfl_xor(sq, m);
    float rs = rsqrtf(sq * (1.0f / 64.0f) + 1e-5f);
    p[row * 64 + lane] = f2bf((d * rs * g[lane] + bb[lane]) * c);
}

// ---------------- flash attention, swapped-QK^T in-register softmax ----------------
// q[bh][s][64] (pre-scaled), k[bh][s][64], vT[bh][d][s] -> aout[b*S+s][h*64+d] bf16
// S^T = mfma(A=K, B=Q): lane owns q-row n=l16, kv rows m = nb*16 + lq*4 + r.
// O^T = mfma(A=V^T, B=P): needs P[q=l16][kv=kk*32+lq*8..+7] -> repacked via per-wave LDS strip.
__global__ __launch_bounds__(256) void k_flash(const unsigned short* __restrict__ q,
                                               const unsigned short* __restrict__ k,
                                               const unsigned short* __restrict__ vt,
                                               unsigned short* __restrict__ aout) {
    __shared__ __align__(16) unsigned short Ks[64][72];
    __shared__ __align__(16) unsigned short Vs[64][72];
    __shared__ __align__(16) unsigned short Ps[4][16][72];
    const int tid = threadIdx.x, lane = tid & 63, wid = tid >> 6;
    const int l16 = lane & 15, lq = lane >> 4;
    const int bh = blockIdx.y;
    const int q0 = blockIdx.x * 64 + wid * 16;

    bf16x8 bq[2];
#pragma unroll
    for (int kk = 0; kk < 2; kk++)
        bq[kk] = *(const bf16x8*)(q + ((size_t)bh * SEQ + q0 + l16) * 64 + kk * 32 + lq * 8);

    f32x4 o[4] = {};
    float m_run = -1e30f, l_run = 0.f;

    const unsigned short* kbase = k  + (size_t)bh * SEQ * 64;
    const unsigned short* vbase = vt + (size_t)bh * 64 * SEQ;

    for (int t0 = 0; t0 < SEQ; t0 += 64) {
#pragma unroll
        for (int i = 0; i < 2; i++) {
            int ch = i * 256 + tid; int r = ch >> 3, c = (ch & 7) * 8;
            *(bf16x8*)&Ks[r][c] = *(const bf16x8*)(kbase + (size_t)(t0 + r) * 64 + c);
            *(bf16x8*)&Vs[r][c] = *(const bf16x8*)(vbase + (size_t)r * SEQ + t0 + c);
        }
        __syncthreads();

        // S^T block: sa[nb][r] = S'[q=l16][kv = t0 + nb*16 + lq*4 + r]  (log2 domain)
        f32x4 sa[4] = {};
        __builtin_amdgcn_s_setprio(1);
#pragma unroll
        for (int kk = 0; kk < 2; kk++) {
#pragma unroll
            for (int nb = 0; nb < 4; nb++) {
                bf16x8 ak = *(const bf16x8*)&Ks[nb * 16 + l16][kk * 32 + lq * 8];
                sa[nb] = __builtin_amdgcn_mfma_f32_16x16x32_bf16(ak, bq[kk], sa[nb], 0, 0, 0);
            }
        }
        __builtin_amdgcn_s_setprio(0);

        // row max: 16 in-register values + 2 cross-lq shuffles
        float mx = fmaxf(fmaxf(sa[0][0], sa[0][1]), fmaxf(sa[0][2], sa[0][3]));
#pragma unroll
        for (int nb = 1; nb < 4; nb++)
            mx = fmaxf(mx, fmaxf(fmaxf(sa[nb][0], sa[nb][1]), fmaxf(sa[nb][2], sa[nb][3])));
        mx = fmaxf(mx, __shfl_xor(mx, 16));
        mx = fmaxf(mx, __shfl_xor(mx, 32));

        // defer-max (T13): only rescale when max grew by > 8 (log2 units -> P <= 256)
        if (!__all(mx <= m_run + 8.0f)) {
            float mn = fmaxf(m_run, mx);
            float sc = __builtin_amdgcn_exp2f(m_run - mn);
#pragma unroll
            for (int db = 0; db < 4; db++) o[db] *= sc;
            l_run *= sc;
            m_run = mn;
        }

        // P = exp2(S' - m_run), packed to bf16 pairs
        float rs = 0.f;
        unsigned w[4][2];
#pragma unroll
        for (int nb = 0; nb < 4; nb++) {
            float p0 = __builtin_amdgcn_exp2f(sa[nb][0] - m_run);
            float p1 = __builtin_amdgcn_exp2f(sa[nb][1] - m_run);
            float p2 = __builtin_amdgcn_exp2f(sa[nb][2] - m_run);
            float p3 = __builtin_amdgcn_exp2f(sa[nb][3] - m_run);
            rs += (p0 + p1) + (p2 + p3);
            w[nb][0] = pack_bf16(p0, p1);
            w[nb][1] = pack_bf16(p2, p3);
        }
        rs += __shfl_xor(rs, 16);
        rs += __shfl_xor(rs, 32);
        l_run += rs;

        // redistribute P within the wave via per-wave LDS strip (no barrier needed;
        // DS ops from one wave complete in order). Fence stops TBAA reordering.
#pragma unroll
        for (int nb = 0; nb < 4; nb++)
            *(uint2*)&Ps[wid][l16][nb * 16 + lq * 4] = make_uint2(w[nb][0], w[nb][1]);
        asm volatile("" ::: "memory");
        bf16x8 bp[2];
        bp[0] = *(const bf16x8*)&Ps[wid][l16][lq * 8];
        bp[1] = *(const bf16x8*)&Ps[wid][l16][32 + lq * 8];

        // O^T += V^T * P
        __builtin_amdgcn_s_setprio(1);
#pragma unroll
        for (int kk = 0; kk < 2; kk++) {
#pragma unroll
            for (int db = 0; db < 4; db++) {
                bf16x8 av = *(const bf16x8*)&Vs[db * 16 + l16][kk * 32 + lq * 8];
                o[db] = __builtin_amdgcn_mfma_f32_16x16x32_bf16(av, bp[kk], o[db], 0, 0, 0);
            }
        }
        __builtin_amdgcn_s_setprio(0);
        __syncthreads();
    }

    float inv = 1.0f / l_run;
    const int b = bh >> 4, h = bh & 15;
#pragma unroll
    for (int db = 0; db < 4; db++) {
        ushort4 u4;
        u4.x = f2bf(o[db][0] * inv);
        u4.y = f2bf(o[db][1] * inv);
        u4.z = f2bf(o[db][2] * inv);
        u4.w = f2bf(o[db][3] * inv);
        *(ushort4*)(aout + ((size_t)b * SEQ + q0 + l16) * 1024 + h * 64 + db * 16 + lq * 4) = u4;
    }
}

extern "C" void kernel_launch(void* const* d_in, const int* in_sizes, int n_in,
                              void* d_out, int out_size, void* d_ws, size_t ws_size,
                              hipStream_t stream) {
    const float* x     = (const float*)d_in[0];
    const float* wqkv  = (const float*)d_in[1];
    const float* wproj = (const float*)d_in[2];
    const float* qg    = (const float*)d_in[3];
    const float* qb    = (const float*)d_in[4];
    const float* kg    = (const float*)d_in[5];
    const float* kb    = (const float*)d_in[6];
    float* out = (float*)d_out;

    char* ws = (char*)d_ws;
    unsigned short* xbf    = (unsigned short*)(ws);                       // 16 MB
    unsigned short* wqkvT  = (unsigned short*)(ws + (16llu << 20));       // 6 MB
    unsigned short* wprojT = (unsigned short*)(ws + (22llu << 20));       // 2 MB
    unsigned short* qraw   = (unsigned short*)(ws + (24llu << 20));       // 16 MB
    unsigned short* kraw   = (unsigned short*)(ws + (40llu << 20));       // 16 MB
    unsigned short* vtr    = (unsigned short*)(ws + (56llu << 20));       // 16 MB
    unsigned short* aattn  = (unsigned short*)(ws + (72llu << 20));       // 16 MB (total 88 MB)

    hipLaunchKernelGGL(k_cvt_x, dim3(8192), dim3(256), 0, stream, (const float4*)x, (uint2*)xbf);
    hipLaunchKernelGGL(k_transpose, dim3(48, 16), dim3(256), 0, stream, wqkv, wqkvT, 3072);
    hipLaunchKernelGGL(k_transpose, dim3(16, 16), dim3(256), 0, stream, wproj, wprojT, 1024);
    hipLaunchKernelGGL((k_gemm<0>), dim3(64, 24), dim3(256), 0, stream, xbf, wqkvT, (float*)nullptr, qraw, kraw, vtr);
    hipLaunchKernelGGL(k_ln, dim3(32768, 2), dim3(256), 0, stream, qraw, kraw, qg, qb, kg, kb);
    hipLaunchKernelGGL(k_flash, dim3(32, 64), dim3(256), 0, stream, qraw, kraw, vtr, aattn);
    hipLaunchKernelGGL((k_gemm<1>), dim3(64, 8), dim3(256), 0, stream, aattn, wprojT, out,
                       (unsigned short*)nullptr, (unsigned short*)nullptr, (unsigned short*)nullptr);
}